// Round 1
// baseline (110.201 us; speedup 1.0000x reference)
//
#include <hip/hip_runtime.h>
#include <hip/hip_bf16.h>

// Problem constants (B,T,H,D,M) = (2, 2048, 8, 64, 64), fp32 in/out.
#define BB 2
#define TT 2048
#define HH 8
#define DD 64
#define CC 64            // chunks over T
#define TC (TT / CC)     // 32 timesteps per chunk

__device__ __forceinline__ float feat(float x) {
    // elu(x) + 1 = x+1 (x>0) else exp(x)
    return x > 0.f ? x + 1.f : __expf(x);
}

// Kernel 1: per (b,h,c) chunk sums of kf over time.
// grid = B*H*C blocks, block = 64 (lane = d). ws[idx*64 + d] = sum over chunk.
__global__ void __launch_bounds__(64)
chunk_sums_kernel(const float* __restrict__ k, float* __restrict__ ws) {
    const int idx  = blockIdx.x;          // (b*H + h)*C + c
    const int c    = idx & (CC - 1);
    const int h    = (idx >> 6) & (HH - 1);
    const int b    = idx >> 9;
    const int lane = threadIdx.x;

    const int t0 = c * TC;
    size_t base = (((size_t)b * TT + t0) * HH + h) * DD + lane;
    const int stride = HH * DD;           // 512 floats between timesteps

    float s = 0.f;
    #pragma unroll 8
    for (int i = 0; i < TC; ++i) {
        s += feat(k[base + (size_t)i * stride]);
    }
    ws[(size_t)idx * DD + lane] = s;
}

// Kernel 2: main. grid = B*H*C blocks, block = 64 (one wave per chunk, lane = d = m).
__global__ void __launch_bounds__(64)
linattn_kernel(const float* __restrict__ q, const float* __restrict__ k,
               const float* __restrict__ v, const float* __restrict__ ws,
               float* __restrict__ out) {
    const int idx  = blockIdx.x;
    const int c    = idx & (CC - 1);
    const int h    = (idx >> 6) & (HH - 1);
    const int b    = idx >> 9;
    const int lane = threadIdx.x;

    // carry[d] = sum of kf over all timesteps in preceding chunks (cache-hot ws)
    float carry = 0.f;
    const float* wsp = ws + ((size_t)((b * HH + h) * CC)) * DD + lane;
    for (int cp = 0; cp < c; ++cp) carry += wsp[cp * DD];

    float running = carry;                 // time-cumsum of kf[d], inclusive after update
    const int t0 = c * TC;
    size_t base = (((size_t)b * TT + t0) * HH + h) * DD + lane;
    const int stride = HH * DD;

    for (int i = 0; i < TC; ++i) {
        const size_t off = base + (size_t)i * stride;
        const float qv = q[off];
        const float kv = k[off];
        const float vv = v[off];
        const float qf = feat(qv);
        const float kf = feat(kv);
        running += kf;                     // inclusive cumsum over T

        // inclusive prefix over lanes (the D axis) of kf at this timestep
        float pre = kf;
        #pragma unroll
        for (int o = 1; o < 64; o <<= 1) {
            const float u = __shfl_up(pre, o, 64);
            if (lane >= o) pre += u;
        }

        // two wave reductions, interleaved chains
        float a = qf * running;            // -> s2 (denominator)
        float s = qf * pre;                // -> s1 (numerator)
        #pragma unroll
        for (int o = 32; o >= 1; o >>= 1) {
            a += __shfl_xor(a, o, 64);
            s += __shfl_xor(s, o, 64);
        }

        out[off] = vv * (s / a);           // lane doubles as m index (M == D == 64)
    }
}

extern "C" void kernel_launch(void* const* d_in, const int* in_sizes, int n_in,
                              void* d_out, int out_size, void* d_ws, size_t ws_size,
                              hipStream_t stream) {
    const float* q = (const float*)d_in[0];
    const float* k = (const float*)d_in[1];
    const float* v = (const float*)d_in[2];
    float* out = (float*)d_out;
    float* ws  = (float*)d_ws;            // needs B*H*C*D*4 = 256 KB

    const int nblk = BB * HH * CC;        // 1024
    chunk_sums_kernel<<<nblk, 64, 0, stream>>>(k, ws);
    linattn_kernel<<<nblk, 64, 0, stream>>>(q, k, v, ws, out);
}

// Round 2
// 90.274 us; speedup vs baseline: 1.2207x; 1.2207x over previous
//
#include <hip/hip_runtime.h>
#include <hip/hip_bf16.h>

// Problem constants (B,T,H,D,M) = (2, 2048, 8, 64, 64), fp32 in/out.
#define BB 2
#define TT 2048
#define HH 8
#define DD 64
#define CC 128           // chunks over T
#define TC (TT / CC)     // 16 timesteps per chunk
#define STRIDE (HH * DD) // 512 floats between consecutive timesteps

__device__ __forceinline__ float feat(float x) {
    // elu(x) + 1 = x+1 (x>0) else exp(x)
    return x > 0.f ? x + 1.f : __expf(x);
}

// Kernel 1: per (b,h,c) chunk sums of kf over time.
// grid = B*H*CC waves, lane = d. ws[idx*64 + d] = sum of feat(k) over chunk.
__global__ void __launch_bounds__(64)
chunk_sums_kernel(const float* __restrict__ k, float* __restrict__ ws) {
    const int idx  = blockIdx.x;              // (b*H + h)*CC + c
    const int c    = idx & (CC - 1);
    const int h    = (idx >> 7) & (HH - 1);
    const int b    = idx >> 10;
    const int lane = threadIdx.x;

    size_t base = (((size_t)b * TT + c * TC) * HH + h) * DD + lane;

    float kv[TC];
    #pragma unroll
    for (int i = 0; i < TC; ++i) kv[i] = k[base + (size_t)i * STRIDE];

    float s = 0.f;
    #pragma unroll
    for (int i = 0; i < TC; ++i) s += feat(kv[i]);
    ws[(size_t)idx * DD + lane] = s;
}

// Kernel 2: main. One wave per (b,h,c) chunk; lane = d = m.
__global__ void __launch_bounds__(64)
linattn_kernel(const float* __restrict__ q, const float* __restrict__ k,
               const float* __restrict__ v, const float* __restrict__ ws,
               float* __restrict__ out) {
    const int idx  = blockIdx.x;
    const int c    = idx & (CC - 1);
    const int h    = (idx >> 7) & (HH - 1);
    const int b    = idx >> 10;
    const int lane = threadIdx.x;

    size_t base = (((size_t)b * TT + c * TC) * HH + h) * DD + lane;

    // Issue all chunk loads up front (independent; one latency exposure).
    float kf[TC], qf[TC], vv[TC];
    #pragma unroll
    for (int i = 0; i < TC; ++i) kf[i] = k[base + (size_t)i * STRIDE];
    #pragma unroll
    for (int i = 0; i < TC; ++i) qf[i] = q[base + (size_t)i * STRIDE];
    #pragma unroll
    for (int i = 0; i < TC; ++i) vv[i] = v[base + (size_t)i * STRIDE];

    // carry[d] = sum of kf over preceding chunks (L2-hot ws; overlaps HBM loads)
    float carry = 0.f;
    {
        const float* wsp = ws + ((size_t)((b * HH + h) * CC)) * DD + lane;
        int cp = 0;
        for (; cp + 4 <= c; cp += 4)
            carry += wsp[(cp + 0) * DD] + wsp[(cp + 1) * DD] +
                     wsp[(cp + 2) * DD] + wsp[(cp + 3) * DD];
        for (; cp < c; ++cp) carry += wsp[cp * DD];
    }

    // Feature map (in place) + inclusive time-cumsum per lane.
    #pragma unroll
    for (int i = 0; i < TC; ++i) { kf[i] = feat(kf[i]); qf[i] = feat(qf[i]); }

    float run[TC];
    run[0] = carry + kf[0];
    #pragma unroll
    for (int i = 1; i < TC; ++i) run[i] = run[i - 1] + kf[i];

    // Batched inclusive lane-prefix scans of kf (over the D axis), in place:
    // 6 steps, TC independent shfls per step -> ILP hides shfl latency.
    #pragma unroll
    for (int o = 1; o < 64; o <<= 1) {
        float u[TC];
        #pragma unroll
        for (int i = 0; i < TC; ++i) u[i] = __shfl_up(kf[i], o, 64);
        #pragma unroll
        for (int i = 0; i < TC; ++i) if (lane >= o) kf[i] += u[i];
    }
    // kf[i] now holds pre[i] = inclusive prefix over d of feat(k).

    // Batched butterfly reductions: a[i] -> s2 (denominator), s[i] -> s1.
    float a[TC], s[TC];
    #pragma unroll
    for (int i = 0; i < TC; ++i) { a[i] = qf[i] * run[i]; s[i] = qf[i] * kf[i]; }
    #pragma unroll
    for (int o = 32; o >= 1; o >>= 1) {
        #pragma unroll
        for (int i = 0; i < TC; ++i) {
            a[i] += __shfl_xor(a[i], o, 64);
            s[i] += __shfl_xor(s[i], o, 64);
        }
    }

    #pragma unroll
    for (int i = 0; i < TC; ++i)
        out[base + (size_t)i * STRIDE] = vv[i] * (s[i] / a[i]);
}

extern "C" void kernel_launch(void* const* d_in, const int* in_sizes, int n_in,
                              void* d_out, int out_size, void* d_ws, size_t ws_size,
                              hipStream_t stream) {
    const float* q = (const float*)d_in[0];
    const float* k = (const float*)d_in[1];
    const float* v = (const float*)d_in[2];
    float* out = (float*)d_out;
    float* ws  = (float*)d_ws;            // needs B*H*CC*DD*4 = 512 KB

    const int nblk = BB * HH * CC;        // 2048
    chunk_sums_kernel<<<nblk, 64, 0, stream>>>(k, ws);
    linattn_kernel<<<nblk, 64, 0, stream>>>(q, k, v, ws, out);
}

// Round 3
// 83.232 us; speedup vs baseline: 1.3240x; 1.0846x over previous
//
#include <hip/hip_runtime.h>
#include <hip/hip_bf16.h>

// Problem constants (B,T,H,D,M) = (2, 2048, 8, 64, 64), fp32 in/out.
#define BB 2
#define TT 2048
#define HH 8
#define DD 64
#define CC 256           // chunks over T
#define TC (TT / CC)     // 8 timesteps per chunk
#define STRIDE (HH * DD) // 512 floats between consecutive timesteps
#define NBH (BB * HH)    // 16
#define PW (CC / 16)     // 16 chunks per wave in prefix_kernel

__device__ __forceinline__ float feat(float x) {
    // elu(x) + 1 = x+1 (x>0) else exp(x)
    return x > 0.f ? x + 1.f : __expf(x);
}

// Kernel 1: per (b,h,c) chunk sums of feat(k) over time.
// grid = B*H*CC waves, lane = d. ws[idx*64 + d] = sum over chunk.
__global__ void __launch_bounds__(64)
chunk_sums_kernel(const float* __restrict__ k, float* __restrict__ ws) {
    const int idx  = blockIdx.x;              // (b*H + h)*CC + c
    const int c    = idx & (CC - 1);
    const int h    = (idx >> 8) & (HH - 1);
    const int b    = idx >> 11;
    const int lane = threadIdx.x;

    size_t base = (((size_t)b * TT + c * TC) * HH + h) * DD + lane;

    float kv[TC];
    #pragma unroll
    for (int i = 0; i < TC; ++i) kv[i] = k[base + (size_t)i * STRIDE];

    float s = 0.f;
    #pragma unroll
    for (int i = 0; i < TC; ++i) s += feat(kv[i]);
    ws[(size_t)idx * DD + lane] = s;
}

// Kernel 2: in-place convert ws chunk sums -> EXCLUSIVE prefix over c, per (b,h,d).
// grid = B*H blocks of 1024 threads (16 waves); wave w handles chunks [w*PW, w*PW+PW).
__global__ void __launch_bounds__(1024)
prefix_kernel(float* __restrict__ ws) {
    const int bh   = blockIdx.x;              // 0..15
    const int lane = threadIdx.x & 63;        // d
    const int w    = threadIdx.x >> 6;        // wave id 0..15

    size_t base = ((size_t)bh * CC + w * PW) * DD + lane;

    float val[PW];
    #pragma unroll
    for (int i = 0; i < PW; ++i) val[i] = ws[base + (size_t)i * DD];

    float run = 0.f, excl[PW];
    #pragma unroll
    for (int i = 0; i < PW; ++i) { excl[i] = run; run += val[i]; }

    __shared__ float tot[16][DD];
    tot[w][lane] = run;                       // inclusive total of this wave's span
    __syncthreads();

    float carry = 0.f;
    for (int w2 = 0; w2 < w; ++w2) carry += tot[w2][lane];

    #pragma unroll
    for (int i = 0; i < PW; ++i) ws[base + (size_t)i * DD] = excl[i] + carry;
}

// Kernel 3: main. One wave per (b,h,c) chunk; lane = d = m.
__global__ void __launch_bounds__(64)
linattn_kernel(const float* __restrict__ q, const float* __restrict__ k,
               const float* __restrict__ v, const float* __restrict__ ws,
               float* __restrict__ out) {
    const int idx  = blockIdx.x;
    const int c    = idx & (CC - 1);
    const int h    = (idx >> 8) & (HH - 1);
    const int b    = idx >> 11;
    const int lane = threadIdx.x;

    size_t base = (((size_t)b * TT + c * TC) * HH + h) * DD + lane;

    // Issue all chunk loads up front (independent; one latency exposure).
    float kf[TC], qf[TC], vv[TC];
    #pragma unroll
    for (int i = 0; i < TC; ++i) kf[i] = k[base + (size_t)i * STRIDE];
    #pragma unroll
    for (int i = 0; i < TC; ++i) qf[i] = q[base + (size_t)i * STRIDE];
    #pragma unroll
    for (int i = 0; i < TC; ++i) vv[i] = v[base + (size_t)i * STRIDE];

    // Exclusive prefix of chunk sums: ONE load (L2-hot).
    const float carry = ws[(size_t)idx * DD + lane];

    // Feature map + inclusive time-cumsum per lane (d).
    #pragma unroll
    for (int i = 0; i < TC; ++i) { kf[i] = feat(kf[i]); qf[i] = feat(qf[i]); }

    float run[TC];
    run[0] = carry + kf[0];
    #pragma unroll
    for (int i = 1; i < TC; ++i) run[i] = run[i - 1] + kf[i];

    // Batched inclusive lane-prefix scans of kf over d: 6 steps × TC indep shfls.
    #pragma unroll
    for (int o = 1; o < 64; o <<= 1) {
        float u[TC];
        #pragma unroll
        for (int i = 0; i < TC; ++i) u[i] = __shfl_up(kf[i], o, 64);
        #pragma unroll
        for (int i = 0; i < TC; ++i) if (lane >= o) kf[i] += u[i];
    }
    // kf[i] now holds inclusive prefix over d of feat(k) at timestep i.

    // Batched butterfly reductions: a -> s2 (denominator), s -> s1 (numerator).
    float a[TC], s[TC];
    #pragma unroll
    for (int i = 0; i < TC; ++i) { a[i] = qf[i] * run[i]; s[i] = qf[i] * kf[i]; }
    #pragma unroll
    for (int o = 32; o >= 1; o >>= 1) {
        #pragma unroll
        for (int i = 0; i < TC; ++i) {
            a[i] += __shfl_xor(a[i], o, 64);
            s[i] += __shfl_xor(s[i], o, 64);
        }
    }

    #pragma unroll
    for (int i = 0; i < TC; ++i)
        out[base + (size_t)i * STRIDE] = vv[i] * (s[i] / a[i]);
}

extern "C" void kernel_launch(void* const* d_in, const int* in_sizes, int n_in,
                              void* d_out, int out_size, void* d_ws, size_t ws_size,
                              hipStream_t stream) {
    const float* q = (const float*)d_in[0];
    const float* k = (const float*)d_in[1];
    const float* v = (const float*)d_in[2];
    float* out = (float*)d_out;
    float* ws  = (float*)d_ws;            // needs B*H*CC*DD*4 = 1 MB

    const int nblk = BB * HH * CC;        // 4096
    chunk_sums_kernel<<<nblk, 64, 0, stream>>>(k, ws);
    prefix_kernel<<<NBH, 1024, 0, stream>>>(ws);
    linattn_kernel<<<nblk, 64, 0, stream>>>(q, k, v, ws, out);
}